// Round 22
// baseline (89.219 us; speedup 1.0000x reference)
//
#include <hip/hip_runtime.h>
#include <hip/hip_bf16.h>

#define NN 8192
#define SD 512
#define HID 128
#define DE 128
#define KP1 11
#define EPSF 0.001f
#define NSPLIT 32
#define NCHUNK NSPLIT
#define CB (NN / NSPLIT)               // 256 candidates per block (64KB LDS)
#define NSUB (CB / 16)                 // 16 subtiles
#define QB 512                         // queries per knn block (16 waves)
#define PBLK (16 * 2 * KP1 * 16)       // 5632 floats = 22528 B per block, contiguous

using short8 = __attribute__((ext_vector_type(8))) short;
using f32x4 = __attribute__((ext_vector_type(4))) float;

__device__ inline ushort f2bf(float f) {
    __hip_bfloat16 b = __float2bfloat16(f);
    return *reinterpret_cast<ushort*>(&b);
}
__device__ inline float bf2f(ushort u) {
    unsigned v = (unsigned)u << 16;
    union { unsigned u; float f; } c; c.u = v; return c.f;
}
__device__ inline void split8(const float4 a, const float4 b, short8& hi, short8& lo) {
    float v[8] = {a.x, a.y, a.z, a.w, b.x, b.y, b.z, b.w};
    ushort h[8], lw[8];
#pragma unroll
    for (int j = 0; j < 8; ++j) {
        h[j] = f2bf(v[j]);
        lw[j] = f2bf(v[j] - bf2f(h[j]));
    }
    hi = *reinterpret_cast<short8*>(h);
    lo = *reinterpret_cast<short8*>(lw);
}

// ---------------- Kernel 1: split-bf16 MFMA MLP, W split in-register.
// Block = 32 rows x 128 cols, 8 waves; wave w owns 16 cols.
__global__ __launch_bounds__(512) void mlp_kernel(
    const float* __restrict__ s, const float* __restrict__ W1,
    const float* __restrict__ b1, const float* __restrict__ W2,
    const float* __restrict__ b2, __hip_bfloat16* __restrict__ xb,
    float* __restrict__ sqb)
{
    __shared__ __align__(16) ushort sbh[2][32 * 32];
    __shared__ __align__(16) ushort sbl[2][32 * 32];
    __shared__ __align__(16) ushort hbh[32 * 128];
    __shared__ __align__(16) ushort hbl[32 * 128];
    __shared__ __align__(16) ushort xtile[32 * 128];
    __shared__ float sqpart[8 * 32];

    const int t = threadIdx.x;
    const int w = t >> 6, l = t & 63;
    const int lc = l & 15, c4 = l >> 4;
    const int rb = blockIdx.x * 32;
    const int cb = w * 16;

    const int srow = t >> 4, sk = t & 15;
    const int ssl = ((sk >> 2) + (srow >> 2)) & 3;
    const int sByte = srow * 64 + (ssl ^ (srow & 3)) * 16 + (sk & 3) * 4;
    const float* sgbase = s + (size_t)(rb + srow) * SD + sk * 2;

    float2 sf;
#define STAGE_LOAD_S(kt_) sf = *reinterpret_cast<const float2*>(sgbase + (kt_) * 32)
#define STAGE_WRITE_S(b_) do { \
    ushort h0_ = f2bf(sf.x), h1_ = f2bf(sf.y); \
    ushort l0_ = f2bf(sf.x - bf2f(h0_)), l1_ = f2bf(sf.y - bf2f(h1_)); \
    *reinterpret_cast<unsigned*>(reinterpret_cast<char*>(sbh[b_]) + sByte) = \
        (unsigned)h0_ | ((unsigned)h1_ << 16); \
    *reinterpret_cast<unsigned*>(reinterpret_cast<char*>(sbl[b_]) + sByte) = \
        (unsigned)l0_ | ((unsigned)l1_ << 16); \
} while (0)

    int aByte[2];
#pragma unroll
    for (int rt = 0; rt < 2; ++rt) {
        int row = rt * 16 + lc;
        int sl = ((c4 + (row >> 2)) & 3) ^ (row & 3);
        aByte[rt] = row * 64 + sl * 16;
    }

    const int col = cb + lc;
    const float* w1p = W1 + (size_t)col * SD + c4 * 8;

    f32x4 acc1[2];
#pragma unroll
    for (int rt = 0; rt < 2; ++rt) acc1[rt] = {0.f, 0.f, 0.f, 0.f};

    STAGE_LOAD_S(0);
    STAGE_WRITE_S(0);
    float4 wf0 = *reinterpret_cast<const float4*>(w1p);
    float4 wf1 = *reinterpret_cast<const float4*>(w1p + 4);
    float4 nwf0, nwf1;

    for (int kt = 0; kt < 16; ++kt) {
        __syncthreads();
        if (kt < 15) STAGE_LOAD_S(kt + 1);
        short8 ah[2], al[2];
#pragma unroll
        for (int rt = 0; rt < 2; ++rt) {
            ah[rt] = *reinterpret_cast<const short8*>(
                reinterpret_cast<char*>(sbh[kt & 1]) + aByte[rt]);
            al[rt] = *reinterpret_cast<const short8*>(
                reinterpret_cast<char*>(sbl[kt & 1]) + aByte[rt]);
        }
        if (kt < 15) {
            nwf0 = *reinterpret_cast<const float4*>(w1p + (kt + 1) * 32);
            nwf1 = *reinterpret_cast<const float4*>(w1p + (kt + 1) * 32 + 4);
        }
        short8 bh, bl;
        split8(wf0, wf1, bh, bl);
#pragma unroll
        for (int rt = 0; rt < 2; ++rt) {
            acc1[rt] = __builtin_amdgcn_mfma_f32_16x16x32_bf16(ah[rt], bh, acc1[rt], 0, 0, 0);
            acc1[rt] = __builtin_amdgcn_mfma_f32_16x16x32_bf16(ah[rt], bl, acc1[rt], 0, 0, 0);
            acc1[rt] = __builtin_amdgcn_mfma_f32_16x16x32_bf16(al[rt], bh, acc1[rt], 0, 0, 0);
        }
        if (kt < 15) {
            STAGE_WRITE_S((kt + 1) & 1);
            wf0 = nwf0; wf1 = nwf1;
        }
    }

    const float b1v = b1[col];
#pragma unroll
    for (int rt = 0; rt < 2; ++rt)
#pragma unroll
        for (int reg = 0; reg < 4; ++reg) {
            float v = fmaxf(acc1[rt][reg] + b1v, 0.f);
            ushort hh = f2bf(v);
            ushort hl = f2bf(v - bf2f(hh));
            int row = rt * 16 + c4 * 4 + reg;
            int sl = (col >> 3) ^ (row & 15);
            int byte = row * 256 + sl * 16 + (col & 7) * 2;
            *reinterpret_cast<ushort*>(reinterpret_cast<char*>(hbh) + byte) = hh;
            *reinterpret_cast<ushort*>(reinterpret_cast<char*>(hbl) + byte) = hl;
        }
    __syncthreads();

    f32x4 acc2[2];
#pragma unroll
    for (int rt = 0; rt < 2; ++rt) acc2[rt] = {0.f, 0.f, 0.f, 0.f};

    const float* w2p = W2 + (size_t)col * HID + c4 * 8;
#pragma unroll
    for (int kt = 0; kt < 4; ++kt) {
        short8 ah[2], al[2];
#pragma unroll
        for (int rt = 0; rt < 2; ++rt) {
            int row = rt * 16 + lc;
            int sl = (kt * 4 + c4) ^ (row & 15);
            int byte = row * 256 + sl * 16;
            ah[rt] = *reinterpret_cast<const short8*>(reinterpret_cast<char*>(hbh) + byte);
            al[rt] = *reinterpret_cast<const short8*>(reinterpret_cast<char*>(hbl) + byte);
        }
        float4 w0 = *reinterpret_cast<const float4*>(w2p + kt * 32);
        float4 w1v = *reinterpret_cast<const float4*>(w2p + kt * 32 + 4);
        short8 wh, wl;
        split8(w0, w1v, wh, wl);
#pragma unroll
        for (int rt = 0; rt < 2; ++rt) {
            acc2[rt] = __builtin_amdgcn_mfma_f32_16x16x32_bf16(ah[rt], wh, acc2[rt], 0, 0, 0);
            acc2[rt] = __builtin_amdgcn_mfma_f32_16x16x32_bf16(ah[rt], wl, acc2[rt], 0, 0, 0);
            acc2[rt] = __builtin_amdgcn_mfma_f32_16x16x32_bf16(al[rt], wh, acc2[rt], 0, 0, 0);
        }
    }

    const float b2v = b2[col];
    float p[8];
#pragma unroll
    for (int j = 0; j < 8; ++j) p[j] = 0.f;
#pragma unroll
    for (int rt = 0; rt < 2; ++rt)
#pragma unroll
        for (int reg = 0; reg < 4; ++reg) {
            float v = acc2[rt][reg] + b2v;
            ushort xv = f2bf(v);
            float xf = bf2f(xv);
            p[rt * 4 + reg] = fmaf(xf, xf, p[rt * 4 + reg]);
            int row = rt * 16 + c4 * 4 + reg;
            xtile[row * 128 + col] = xv;
        }
#pragma unroll
    for (int j = 0; j < 8; ++j) {
#pragma unroll
        for (int off = 8; off >= 1; off >>= 1) p[j] += __shfl_xor(p[j], off, 16);
    }
    if (lc == 0) {
#pragma unroll
        for (int rt = 0; rt < 2; ++rt)
#pragma unroll
            for (int reg = 0; reg < 4; ++reg)
                sqpart[w * 32 + rt * 16 + c4 * 4 + reg] = p[rt * 4 + reg];
    }
    __syncthreads();
    if (t < 32) {
        float sq = 0.f;
#pragma unroll
        for (int ww = 0; ww < 8; ++ww) sq += sqpart[ww * 32 + t];
        sqb[rb + t] = sq;
    }
    const short8* xsv = reinterpret_cast<const short8*>(xtile);
    short8* xg = reinterpret_cast<short8*>(reinterpret_cast<ushort*>(xb) + (size_t)rb * DE);
    xg[t] = xsv[t];
}

// ---------------- Kernel 2: per-row top-11 of d2' = sq[c] - 2*dot.
// r15 single-barrier scan, now 16-WAVE / 1024-thread blocks (512 queries each):
// same CB=256 / 66.5KB LDS -> still 2 blocks/CU but 32 waves/CU (8/SIMD, HW max),
// grid 512 = exactly one generation (no tail). Scan is barrier-free so waves drift.
__global__ __launch_bounds__(1024) void knn_kernel(
    const ushort* __restrict__ xs, const float* __restrict__ sqb,
    float* __restrict__ part)
{
    __shared__ __align__(16) ushort lbuf[CB * DE];   // 64KB (merge overlay reuses)
    __shared__ __align__(16) float sqs[CB];          // 1KB

    const int bid = blockIdx.x;              // 512 = 16 rid x 32 cid
    const int rid = bid >> 5, cid = bid & 31;
    const int t = threadIdx.x;
    const int w = t >> 6, l = t & 63;
    const int q16 = l & 15, lg = l >> 4;
    const int kk = lg * 8;
    const int qb = rid * QB + w * 32;
    const int cstart = cid * CB;

    // ---- one-time stage: 256 cand rows -> swizzled LDS (thread t: 4 x 16B slots)
    {
        const ushort* sb = xs + (size_t)cstart * DE;
#pragma unroll
        for (int i = 0; i < 4; ++i) {
            int sl = t + 1024 * i;
            int row = sl >> 4, col = sl & 15;
            short8 v = *reinterpret_cast<const short8*>(sb + row * DE + col * 8);
            *reinterpret_cast<short8*>(&lbuf[(row * 16 + (col ^ (row & 7))) * 8]) = v;
        }
        if (t < 64)
            reinterpret_cast<float4*>(sqs)[t] =
                reinterpret_cast<const float4*>(sqb + cstart)[t];
    }

    short8 bq[2][4];
#pragma unroll
    for (int qs = 0; qs < 2; ++qs)
#pragma unroll
        for (int kb = 0; kb < 4; ++kb)
            bq[qs][kb] = *reinterpret_cast<const short8*>(
                xs + (size_t)(qb + qs * 16 + q16) * DE + kb * 32 + kk);

    float m[2][KP1];
#pragma unroll
    for (int qs = 0; qs < 2; ++qs)
#pragma unroll
        for (int j = 0; j < KP1; ++j) m[qs][j] = 1e30f;

#define INS(qs_, v_) do { \
    float d2_ = (v_); \
    _Pragma("unroll") \
    for (int j_ = KP1 - 1; j_ >= 1; --j_) \
        m[qs_][j_] = __builtin_amdgcn_fmed3f(d2_, m[qs_][j_ - 1], m[qs_][j_]); \
    m[qs_][0] = fminf(d2_, m[qs_][0]); \
} while (0)

    int aIdx[4];
#pragma unroll
    for (int kb = 0; kb < 4; ++kb)
        aIdx[kb] = (q16 * 16 + ((kb * 4 + lg) ^ (q16 & 7))) * 8;

    __syncthreads();                         // THE barrier: lbuf + sqs published

    // ---- barrier-free scan over 16 subtiles
    for (int st = 0; st < NSUB; ++st) {
        const ushort* lb = lbuf + st * 2048;
        short8 fa[4];
#pragma unroll
        for (int kb = 0; kb < 4; ++kb)
            fa[kb] = *reinterpret_cast<const short8*>(lb + aIdx[kb]);
        float4 sv = *reinterpret_cast<const float4*>(sqs + st * 16 + lg * 4);
#pragma unroll
        for (int qs = 0; qs < 2; ++qs) {
            f32x4 acc = {0.f, 0.f, 0.f, 0.f};
#pragma unroll
            for (int kb = 0; kb < 4; ++kb)
                acc = __builtin_amdgcn_mfma_f32_16x16x32_bf16(fa[kb], bq[qs][kb], acc, 0, 0, 0);
            INS(qs, fmaf(-2.f, acc[0], sv.x));
            INS(qs, fmaf(-2.f, acc[1], sv.y));
            INS(qs, fmaf(-2.f, acc[2], sv.z));
            INS(qs, fmaf(-2.f, acc[3], sv.w));
        }
    }
#undef INS

    // ---- lane-group merge, 2 qs-phases ([16w][4lg][11][16] floats = 45KB fits lbuf)
    float* mb = reinterpret_cast<float*>(lbuf);
    float* pout = part + (size_t)bid * PBLK;
#pragma unroll
    for (int qs = 0; qs < 2; ++qs) {
        __syncthreads();                     // scan readers / previous phase done
#pragma unroll
        for (int j = 0; j < KP1; ++j)
            mb[((w * 4 + lg) * KP1 + j) * 16 + q16] = m[qs][j];
        __syncthreads();
        if (l < 16) {                        // lanes 0..15: q16 == l
            float mm[KP1];
#pragma unroll
            for (int j = 0; j < KP1; ++j)
                mm[j] = mb[((w * 4 + 0) * KP1 + j) * 16 + l];
#pragma unroll
            for (int g = 1; g < 4; ++g)
#pragma unroll
                for (int j = 0; j < KP1; ++j) {
                    float d2 = mb[((w * 4 + g) * KP1 + j) * 16 + l];
#pragma unroll
                    for (int jj = KP1 - 1; jj >= 1; --jj)
                        mm[jj] = __builtin_amdgcn_fmed3f(d2, mm[jj - 1], mm[jj]);
                    mm[0] = fminf(d2, mm[0]);
                }
#pragma unroll
            for (int j = 0; j < KP1; ++j)
                pout[((w * 2 + qs) * KP1 + j) * 16 + l] = mm[j];
        }
    }
}

// ---------------- Kernel 3: merge 32 partial lists -> sumk (coalesced serial-chunk
// reads, 128 blocks x 1 wave).
__global__ __launch_bounds__(64) void merge_kernel(
    const float* __restrict__ part, const float* __restrict__ sqb,
    float* __restrict__ sumk, float* __restrict__ psum)
{
    const int row = blockIdx.x * 64 + threadIdx.x;
    const int rid = row >> 9;                                  // 512 queries per knn block
    const int sub = ((row >> 5) & 15) * 2 + ((row >> 4) & 1);  // w*2+qs
    const int lane = row & 15;
    const float* pbase = part + (size_t)rid * 32 * PBLK + sub * (KP1 * 16) + lane;

    float m[KP1];
#pragma unroll
    for (int j = 0; j < KP1; ++j) m[j] = 1e30f;
#pragma unroll 4
    for (int ch = 0; ch < NCHUNK; ++ch) {
        const float* pc = pbase + ch * PBLK;
#pragma unroll
        for (int j = 0; j < KP1; ++j) {
            float d2 = pc[j * 16];
#pragma unroll
            for (int jj = KP1 - 1; jj >= 1; --jj)
                m[jj] = __builtin_amdgcn_fmed3f(d2, m[jj - 1], m[jj]);
            m[0] = fminf(d2, m[0]);
        }
    }
    const float sqq = sqb[row];
    float sum = 0.f;
#pragma unroll
    for (int j = 1; j < KP1; ++j)
        sum += sqrtf(fmaxf(m[j] + sqq, 1e-12f));
    sumk[row] = sum;

    float p = sum;
#pragma unroll
    for (int off = 32; off >= 1; off >>= 1) p += __shfl_xor(p, off, 64);
    if (threadIdx.x == 0) psum[blockIdx.x] = p;
}

// ---------------- Kernel 4: final — reduce 128 psums -> q, then out
__global__ __launch_bounds__(256) void final_kernel(
    const float* __restrict__ sumk, const float* __restrict__ psum,
    float* __restrict__ out)
{
    __shared__ float qsh;
    __shared__ float red[4];
    const int t = threadIdx.x;
    {
        float p = (t < 128) ? psum[t] : 0.f;
#pragma unroll
        for (int off = 32; off >= 1; off >>= 1) p += __shfl_xor(p, off, 64);
        if ((t & 63) == 0) red[t >> 6] = p;
    }
    __syncthreads();
    if (t == 0) {
        float mean = (red[0] + red[1] + red[2] + red[3]) * (1.0f / NN);
        qsh = EPSF * mean * mean;
    }
    __syncthreads();
    const float qq = qsh;
    const int i = blockIdx.x * 256 + t;
    const float sv = sumk[i];
    out[i] = qq / (fmaf(sv, sv, qq));
}

extern "C" void kernel_launch(void* const* d_in, const int* in_sizes, int n_in,
                              void* d_out, int out_size, void* d_ws, size_t ws_size,
                              hipStream_t stream)
{
    const float* s  = (const float*)d_in[0];
    const float* W1 = (const float*)d_in[1];
    const float* b1 = (const float*)d_in[2];
    const float* W2 = (const float*)d_in[3];
    const float* b2 = (const float*)d_in[4];
    float* out = (float*)d_out;

    char* ws = (char*)d_ws;
    __hip_bfloat16* xb = (__hip_bfloat16*)ws;                       // 2 MB
    float* sqb  = (float*)(ws + (size_t)NN * DE * 2);               // 32 KB
    float* part = sqb + NN;                                         // 512*22528B = 11.5 MB
    float* sumk = part + (size_t)512 * PBLK;                        // 32 KB
    float* psum = sumk + NN;                                        // 512 B

    mlp_kernel<<<NN / 32, 512, 0, stream>>>(s, W1, b1, W2, b2, xb, sqb);
    knn_kernel<<<(NN / QB) * NSPLIT, 1024, 0, stream>>>((const ushort*)xb, sqb, part);
    merge_kernel<<<NN / 64, 64, 0, stream>>>(part, sqb, sumk, psum);
    final_kernel<<<NN / 256, 256, 0, stream>>>(sumk, psum, out);
}

// Round 23
// 76.359 us; speedup vs baseline: 1.1684x; 1.1684x over previous
//
#include <hip/hip_runtime.h>
#include <hip/hip_bf16.h>

#define NN 8192
#define SD 512
#define HID 128
#define DE 128
#define KP1 11
#define EPSF 0.001f
#define NSPLIT 32
#define NCHUNK NSPLIT
#define CB (NN / NSPLIT)               // 256 candidates per block (64KB LDS)
#define NSUB (CB / 16)                 // 16 subtiles
#define PBLK (8 * 2 * KP1 * 16)        // 2816 floats = 11264 B per block, contiguous

using short8 = __attribute__((ext_vector_type(8))) short;
using f32x4 = __attribute__((ext_vector_type(4))) float;

__device__ inline ushort f2bf(float f) {
    __hip_bfloat16 b = __float2bfloat16(f);
    return *reinterpret_cast<ushort*>(&b);
}
__device__ inline float bf2f(ushort u) {
    unsigned v = (unsigned)u << 16;
    union { unsigned u; float f; } c; c.u = v; return c.f;
}

// ---------------- Kernel 0: pre-split W1, W2 into hi/lo bf16
__global__ __launch_bounds__(256) void wsplit_kernel(
    const float* __restrict__ W1, const float* __restrict__ W2,
    ushort* __restrict__ W1h, ushort* __restrict__ W1l,
    ushort* __restrict__ W2h, ushort* __restrict__ W2l)
{
    const int bid = blockIdx.x;
    const float* src; ushort *dh, *dl; int base;
    if (bid < 64) { src = W1; dh = W1h; dl = W1l; base = bid * 1024; }
    else          { src = W2; dh = W2h; dl = W2l; base = (bid - 64) * 1024; }
    const int i = base + threadIdx.x * 4;
    float4 f = *reinterpret_cast<const float4*>(src + i);
    ushort h[4], lo[4];
    float fv[4] = {f.x, f.y, f.z, f.w};
#pragma unroll
    for (int j = 0; j < 4; ++j) {
        h[j] = f2bf(fv[j]);
        lo[j] = f2bf(fv[j] - bf2f(h[j]));
    }
    *reinterpret_cast<uint2*>(dh + i) = *reinterpret_cast<uint2*>(h);
    *reinterpret_cast<uint2*>(dl + i) = *reinterpret_cast<uint2*>(lo);
}

// ---------------- Kernel 1: split-bf16 MFMA MLP. Block = 32 rows x 128 cols,
// 8 waves (512 thr): wave w owns 16 cols -> 8 waves/CU, half per-wave MFMA chain.
__global__ __launch_bounds__(512) void mlp_kernel(
    const float* __restrict__ s, const ushort* __restrict__ W1h,
    const ushort* __restrict__ W1l, const float* __restrict__ b1,
    const ushort* __restrict__ W2h, const ushort* __restrict__ W2l,
    const float* __restrict__ b2, __hip_bfloat16* __restrict__ xb,
    float* __restrict__ sqb)
{
    __shared__ __align__(16) ushort sbh[2][32 * 32];
    __shared__ __align__(16) ushort sbl[2][32 * 32];
    __shared__ __align__(16) ushort hbh[32 * 128];
    __shared__ __align__(16) ushort hbl[32 * 128];
    __shared__ __align__(16) ushort xtile[32 * 128];
    __shared__ float sqpart[8 * 32];

    const int t = threadIdx.x;
    const int w = t >> 6, l = t & 63;
    const int lc = l & 15, c4 = l >> 4;
    const int rb = blockIdx.x * 32;
    const int cb = w * 16;               // wave's 16-col slice

    // staging: 512 threads x 2 f32 of the [32 rows][32 k] chunk
    const int srow = t >> 4, sk = t & 15;           // k = sk*2
    const int ssl = ((sk >> 2) + (srow >> 2)) & 3;
    const int sByte = srow * 64 + (ssl ^ (srow & 3)) * 16 + (sk & 3) * 4;
    const float* sgbase = s + (size_t)(rb + srow) * SD + sk * 2;

    float2 sf;
#define STAGE_LOAD_S(kt_) sf = *reinterpret_cast<const float2*>(sgbase + (kt_) * 32)
#define STAGE_WRITE_S(b_) do { \
    ushort h0_ = f2bf(sf.x), h1_ = f2bf(sf.y); \
    ushort l0_ = f2bf(sf.x - bf2f(h0_)), l1_ = f2bf(sf.y - bf2f(h1_)); \
    *reinterpret_cast<unsigned*>(reinterpret_cast<char*>(sbh[b_]) + sByte) = \
        (unsigned)h0_ | ((unsigned)h1_ << 16); \
    *reinterpret_cast<unsigned*>(reinterpret_cast<char*>(sbl[b_]) + sByte) = \
        (unsigned)l0_ | ((unsigned)l1_ << 16); \
} while (0)

    int aByte[2];
#pragma unroll
    for (int rt = 0; rt < 2; ++rt) {
        int row = rt * 16 + lc;
        int sl = ((c4 + (row >> 2)) & 3) ^ (row & 3);
        aByte[rt] = row * 64 + sl * 16;
    }

    const int col = cb + lc;             // this lane's output col (layer 1 & 2)
    const ushort* w1hp = W1h + (size_t)col * SD + c4 * 8;
    const ushort* w1lp = W1l + (size_t)col * SD + c4 * 8;

    f32x4 acc1[2];
#pragma unroll
    for (int rt = 0; rt < 2; ++rt) acc1[rt] = {0.f, 0.f, 0.f, 0.f};

    STAGE_LOAD_S(0);
    STAGE_WRITE_S(0);
    short8 bh = *reinterpret_cast<const short8*>(w1hp);
    short8 bl = *reinterpret_cast<const short8*>(w1lp);
    short8 nbh, nbl;

    for (int kt = 0; kt < 16; ++kt) {
        __syncthreads();
        if (kt < 15) STAGE_LOAD_S(kt + 1);
        short8 ah[2], al[2];
#pragma unroll
        for (int rt = 0; rt < 2; ++rt) {
            ah[rt] = *reinterpret_cast<const short8*>(
                reinterpret_cast<char*>(sbh[kt & 1]) + aByte[rt]);
            al[rt] = *reinterpret_cast<const short8*>(
                reinterpret_cast<char*>(sbl[kt & 1]) + aByte[rt]);
        }
        if (kt < 15) {
            nbh = *reinterpret_cast<const short8*>(w1hp + (kt + 1) * 32);
            nbl = *reinterpret_cast<const short8*>(w1lp + (kt + 1) * 32);
        }
#pragma unroll
        for (int rt = 0; rt < 2; ++rt) {
            acc1[rt] = __builtin_amdgcn_mfma_f32_16x16x32_bf16(ah[rt], bh, acc1[rt], 0, 0, 0);
            acc1[rt] = __builtin_amdgcn_mfma_f32_16x16x32_bf16(ah[rt], bl, acc1[rt], 0, 0, 0);
            acc1[rt] = __builtin_amdgcn_mfma_f32_16x16x32_bf16(al[rt], bh, acc1[rt], 0, 0, 0);
        }
        if (kt < 15) {
            STAGE_WRITE_S((kt + 1) & 1);
            bh = nbh; bl = nbl;
        }
    }

    const float b1v = b1[col];
#pragma unroll
    for (int rt = 0; rt < 2; ++rt)
#pragma unroll
        for (int reg = 0; reg < 4; ++reg) {
            float v = fmaxf(acc1[rt][reg] + b1v, 0.f);
            ushort hh = f2bf(v);
            ushort hl = f2bf(v - bf2f(hh));
            int row = rt * 16 + c4 * 4 + reg;
            int sl = (col >> 3) ^ (row & 15);
            int byte = row * 256 + sl * 16 + (col & 7) * 2;
            *reinterpret_cast<ushort*>(reinterpret_cast<char*>(hbh) + byte) = hh;
            *reinterpret_cast<ushort*>(reinterpret_cast<char*>(hbl) + byte) = hl;
        }
    __syncthreads();

    f32x4 acc2[2];
#pragma unroll
    for (int rt = 0; rt < 2; ++rt) acc2[rt] = {0.f, 0.f, 0.f, 0.f};

#pragma unroll
    for (int kt = 0; kt < 4; ++kt) {
        short8 ah[2], al[2];
#pragma unroll
        for (int rt = 0; rt < 2; ++rt) {
            int row = rt * 16 + lc;
            int sl = (kt * 4 + c4) ^ (row & 15);
            int byte = row * 256 + sl * 16;
            ah[rt] = *reinterpret_cast<const short8*>(reinterpret_cast<char*>(hbh) + byte);
            al[rt] = *reinterpret_cast<const short8*>(reinterpret_cast<char*>(hbl) + byte);
        }
        short8 wh = *reinterpret_cast<const short8*>(W2h + (size_t)col * HID + kt * 32 + c4 * 8);
        short8 wl = *reinterpret_cast<const short8*>(W2l + (size_t)col * HID + kt * 32 + c4 * 8);
#pragma unroll
        for (int rt = 0; rt < 2; ++rt) {
            acc2[rt] = __builtin_amdgcn_mfma_f32_16x16x32_bf16(ah[rt], wh, acc2[rt], 0, 0, 0);
            acc2[rt] = __builtin_amdgcn_mfma_f32_16x16x32_bf16(ah[rt], wl, acc2[rt], 0, 0, 0);
            acc2[rt] = __builtin_amdgcn_mfma_f32_16x16x32_bf16(al[rt], wh, acc2[rt], 0, 0, 0);
        }
    }

    const float b2v = b2[col];
    float p[8];
#pragma unroll
    for (int j = 0; j < 8; ++j) p[j] = 0.f;
#pragma unroll
    for (int rt = 0; rt < 2; ++rt)
#pragma unroll
        for (int reg = 0; reg < 4; ++reg) {
            float v = acc2[rt][reg] + b2v;
            ushort xv = f2bf(v);
            float xf = bf2f(xv);
            p[rt * 4 + reg] = fmaf(xf, xf, p[rt * 4 + reg]);
            int row = rt * 16 + c4 * 4 + reg;
            xtile[row * 128 + col] = xv;
        }
#pragma unroll
    for (int j = 0; j < 8; ++j) {
#pragma unroll
        for (int off = 8; off >= 1; off >>= 1) p[j] += __shfl_xor(p[j], off, 16);
    }
    if (lc == 0) {
#pragma unroll
        for (int rt = 0; rt < 2; ++rt)
#pragma unroll
            for (int reg = 0; reg < 4; ++reg)
                sqpart[w * 32 + rt * 16 + c4 * 4 + reg] = p[rt * 4 + reg];
    }
    __syncthreads();
    if (t < 32) {
        float sq = 0.f;
#pragma unroll
        for (int ww = 0; ww < 8; ++ww) sq += sqpart[ww * 32 + t];
        sqb[rb + t] = sq;
    }
    const short8* xsv = reinterpret_cast<const short8*>(xtile);
    short8* xg = reinterpret_cast<short8*>(reinterpret_cast<ushort*>(xb) + (size_t)rb * DE);
    xg[t] = xsv[t];
}

// ---------------- Kernel 2: per-row top-11 of d2' = sq[c] - 2*dot. EXACT r15:
// single-barrier 8-wave blocks, 256 cands staged once in 64KB LDS, barrier-free scan.
__global__ __launch_bounds__(512) void knn_kernel(
    const ushort* __restrict__ xs, const float* __restrict__ sqb,
    float* __restrict__ part)
{
    __shared__ __align__(16) ushort lbuf[CB * DE];   // 64KB (merge buffer overlays)
    __shared__ __align__(16) float sqs[CB];          // 1KB

    const int bid = blockIdx.x;              // 1024 = 32 rid x 32 cid
    const int rid = bid >> 5, cid = bid & 31;
    const int t = threadIdx.x;
    const int w = t >> 6, l = t & 63;
    const int q16 = l & 15, lg = l >> 4;
    const int kk = lg * 8;
    const int qb = rid * 256 + w * 32;
    const int cstart = cid * CB;

    {
        const ushort* sb = xs + (size_t)cstart * DE;
#pragma unroll
        for (int i = 0; i < 8; ++i) {
            int sl = t + 512 * i;
            int row = sl >> 4, col = sl & 15;
            short8 v = *reinterpret_cast<const short8*>(sb + row * DE + col * 8);
            *reinterpret_cast<short8*>(&lbuf[(row * 16 + (col ^ (row & 7))) * 8]) = v;
        }
        if (t < 64)
            reinterpret_cast<float4*>(sqs)[t] =
                reinterpret_cast<const float4*>(sqb + cstart)[t];
    }

    short8 bq[2][4];
#pragma unroll
    for (int qs = 0; qs < 2; ++qs)
#pragma unroll
        for (int kb = 0; kb < 4; ++kb)
            bq[qs][kb] = *reinterpret_cast<const short8*>(
                xs + (size_t)(qb + qs * 16 + q16) * DE + kb * 32 + kk);

    float m[2][KP1];
#pragma unroll
    for (int qs = 0; qs < 2; ++qs)
#pragma unroll
        for (int j = 0; j < KP1; ++j) m[qs][j] = 1e30f;

#define INS(qs_, v_) do { \
    float d2_ = (v_); \
    _Pragma("unroll") \
    for (int j_ = KP1 - 1; j_ >= 1; --j_) \
        m[qs_][j_] = __builtin_amdgcn_fmed3f(d2_, m[qs_][j_ - 1], m[qs_][j_]); \
    m[qs_][0] = fminf(d2_, m[qs_][0]); \
} while (0)

    int aIdx[4];
#pragma unroll
    for (int kb = 0; kb < 4; ++kb)
        aIdx[kb] = (q16 * 16 + ((kb * 4 + lg) ^ (q16 & 7))) * 8;

    __syncthreads();                         // THE barrier: lbuf + sqs published

    for (int st = 0; st < NSUB; ++st) {
        const ushort* lb = lbuf + st * 2048;
        short8 fa[4];
#pragma unroll
        for (int kb = 0; kb < 4; ++kb)
            fa[kb] = *reinterpret_cast<const short8*>(lb + aIdx[kb]);
        float4 sv = *reinterpret_cast<const float4*>(sqs + st * 16 + lg * 4);
#pragma unroll
        for (int qs = 0; qs < 2; ++qs) {
            f32x4 acc = {0.f, 0.f, 0.f, 0.f};
#pragma unroll
            for (int kb = 0; kb < 4; ++kb)
                acc = __builtin_amdgcn_mfma_f32_16x16x32_bf16(fa[kb], bq[qs][kb], acc, 0, 0, 0);
            INS(qs, fmaf(-2.f, acc[0], sv.x));
            INS(qs, fmaf(-2.f, acc[1], sv.y));
            INS(qs, fmaf(-2.f, acc[2], sv.z));
            INS(qs, fmaf(-2.f, acc[3], sv.w));
        }
    }

    __syncthreads();                          // all waves done reading lbuf
    float* mb = reinterpret_cast<float*>(lbuf);   // [8w][2qs][4lg][11][16] floats
#pragma unroll
    for (int qs = 0; qs < 2; ++qs)
#pragma unroll
        for (int j = 0; j < KP1; ++j)
            mb[(((w * 2 + qs) * 4 + lg) * KP1 + j) * 16 + q16] = m[qs][j];
    __syncthreads();
    if (l < 32) {
        const int qs = l >> 4, qq = l & 15;
        float mm[KP1];
#pragma unroll
        for (int j = 0; j < KP1; ++j)
            mm[j] = mb[(((w * 2 + qs) * 4 + 0) * KP1 + j) * 16 + qq];
#pragma unroll
        for (int g = 1; g < 4; ++g)
#pragma unroll
            for (int j = 0; j < KP1; ++j) {
                float d2 = mb[(((w * 2 + qs) * 4 + g) * KP1 + j) * 16 + qq];
#pragma unroll
                for (int jj = KP1 - 1; jj >= 1; --jj)
                    mm[jj] = __builtin_amdgcn_fmed3f(d2, mm[jj - 1], mm[jj]);
                mm[0] = fminf(d2, mm[0]);
            }
        float* pout = part + (size_t)bid * PBLK;
#pragma unroll
        for (int j = 0; j < KP1; ++j)
            pout[((w * 2 + qs) * KP1 + j) * 16 + qq] = mm[j];
    }
}

// ---------------- Kernel 3: parallel merge — one 32-lane half-wave per row.
__global__ __launch_bounds__(256) void merge_kernel(
    const float* __restrict__ part, const float* __restrict__ sqb,
    float* __restrict__ sumk, float* __restrict__ psum)
{
    __shared__ float rowsum[8];
    const int t = threadIdx.x;
    const int ww = t >> 6, l = t & 63;
    const int half = l >> 5, c = l & 31;       // c = chunk index
    const int row = blockIdx.x * 8 + ww * 2 + half;
    const int rid = row >> 8;                  // 256 queries per knn block
    const int sub = (row >> 4) & 15;           // w*2+qs
    const int qq = row & 15;
    const float* pl = part + (size_t)(rid * 32 + c) * PBLK + sub * (KP1 * 16) + qq;

    float m[KP1];
#pragma unroll
    for (int j = 0; j < KP1; ++j) m[j] = pl[j * 16];   // sorted ascending

#pragma unroll
    for (int s = 1; s <= 16; s <<= 1) {        // 5-level tree merge within 32 lanes
        float o[KP1];
#pragma unroll
        for (int j = 0; j < KP1; ++j) o[j] = __shfl_xor(m[j], s, 64);
#pragma unroll
        for (int j = 0; j < KP1; ++j) {
            float d2 = o[j];
#pragma unroll
            for (int jj = KP1 - 1; jj >= 1; --jj)
                m[jj] = __builtin_amdgcn_fmed3f(d2, m[jj - 1], m[jj]);
            m[0] = fminf(d2, m[0]);
        }
    }

    if (c == 0) {
        const float sqq = sqb[row];
        float sum = 0.f;
#pragma unroll
        for (int j = 1; j < KP1; ++j)          // m[0] = self; dist^2 = m + sqq
            sum += sqrtf(fmaxf(m[j] + sqq, 1e-12f));
        sumk[row] = sum;
        rowsum[ww * 2 + half] = sum;
    }
    __syncthreads();
    if (t == 0) {
        float p = 0.f;
#pragma unroll
        for (int i = 0; i < 8; ++i) p += rowsum[i];
        psum[blockIdx.x] = p;
    }
}

// ---------------- Kernel 4: final — reduce 1024 psums -> q, then out
__global__ __launch_bounds__(256) void final_kernel(
    const float* __restrict__ sumk, const float* __restrict__ psum,
    float* __restrict__ out)
{
    __shared__ float qsh;
    __shared__ float red[4];
    const int t = threadIdx.x;
    {
        float p = 0.f;
#pragma unroll
        for (int i = 0; i < 4; ++i) p += psum[t + i * 256];
#pragma unroll
        for (int off = 32; off >= 1; off >>= 1) p += __shfl_xor(p, off, 64);
        if ((t & 63) == 0) red[t >> 6] = p;
    }
    __syncthreads();
    if (t == 0) {
        float mean = (red[0] + red[1] + red[2] + red[3]) * (1.0f / NN);
        qsh = EPSF * mean * mean;
    }
    __syncthreads();
    const float qq = qsh;
    const int i = blockIdx.x * 256 + t;
    const float sv = sumk[i];
    out[i] = qq / (fmaf(sv, sv, qq));
}

extern "C" void kernel_launch(void* const* d_in, const int* in_sizes, int n_in,
                              void* d_out, int out_size, void* d_ws, size_t ws_size,
                              hipStream_t stream)
{
    const float* s  = (const float*)d_in[0];
    const float* W1 = (const float*)d_in[1];
    const float* b1 = (const float*)d_in[2];
    const float* W2 = (const float*)d_in[3];
    const float* b2 = (const float*)d_in[4];
    float* out = (float*)d_out;

    char* ws = (char*)d_ws;
    __hip_bfloat16* xb = (__hip_bfloat16*)ws;                       // 2 MB
    float* sqb  = (float*)(ws + (size_t)NN * DE * 2);               // 32 KB
    float* part = sqb + NN;                                         // 11.5 MB
    float* sumk = part + (size_t)1024 * PBLK;                       // 32 KB
    float* psum = sumk + NN;                                        // 4 KB
    ushort* W1h = (ushort*)(psum + 1024);                           // 128 KB
    ushort* W1l = W1h + (size_t)HID * SD;                           // 128 KB
    ushort* W2h = W1l + (size_t)HID * SD;                           // 32 KB
    ushort* W2l = W2h + (size_t)DE * HID;                           // 32 KB

    wsplit_kernel<<<80, 256, 0, stream>>>(W1, W2, W1h, W1l, W2h, W2l);
    mlp_kernel<<<NN / 32, 512, 0, stream>>>(s, W1h, W1l, b1, W2h, W2l, b2, xb, sqb);
    knn_kernel<<<(NN / 256) * NSPLIT, 512, 0, stream>>>((const ushort*)xb, sqb, part);
    merge_kernel<<<NN / 8, 256, 0, stream>>>(part, sqb, sumk, psum);
    final_kernel<<<NN / 256, 256, 0, stream>>>(sumk, psum, out);
}